// Round 17
// baseline (122.187 us; speedup 1.0000x reference)
//
#include <hip/hip_runtime.h>

#define BB 16
#define CC 512
#define NN 192
#define CS 128
#define CR 64
#define EPSF 1e-5f
#define PART (BB*CC*NN)                    // 1572864

typedef __attribute__((ext_vector_type(8))) short short8;
typedef __attribute__((ext_vector_type(4))) float f32x4;
typedef __attribute__((ext_vector_type(4))) unsigned int uint4v;

// ---------------- workspace layout (float units) ----------------
#define OFF_LIN2  0                        // 786432
#define OFF_P2    786432                   // 196608  p2raw[b][i][o] (unscaled)
#define OFF_QT    983040                   // 196608  qTraw[b][j][o] (unscaled)
#define OFF_ATTP4 1179648                  // 4 bf16 partials = 4*PART ushort = 2*PART floats
#define OFF_WBF   7471104                  // short[512*12800] = 3276800 floats
#define OFF_XT    10747904                 // short[16*192*512] = 786432 floats
#define OFF_ROWS  11534336                 // 32768 (sum 16384 + sq 16384), ih8
#define OFF_SPART 11567104                 // 24576

__device__ __forceinline__ unsigned pkbf(float a, float b){
  unsigned r; asm("v_cvt_pk_bf16_f32 %0, %1, %2" : "=v"(r) : "v"(a), "v"(b)); return r;
}

__device__ __forceinline__ void gload_lds16(const void* g, void* l){
  __builtin_amdgcn_global_load_lds(
      (const __attribute__((address_space(1))) unsigned int*)g,
      (__attribute__((address_space(3))) unsigned int*)l, 16, 0, 0);
}

// KCONVXT: att_w -> bf16 wbf (blocks 0..3199, fully coalesced);
//          inputs -> xT bf16 [b][n][c] (3200..3583)
__global__ __launch_bounds__(256) void kconvxt(
    const float* __restrict__ aw, const float* __restrict__ x,
    short* __restrict__ wbf, short* __restrict__ xT)
{
  __shared__ float Ts[64][65];
  int tid = threadIdx.x;
  if (blockIdx.x < 3200) {
    int base = blockIdx.x * 2048;
    int i0 = base + tid*4;
    int i1 = base + 1024 + tid*4;
    float4 v0 = *reinterpret_cast<const float4*>(&aw[i0]);
    float4 v1 = *reinterpret_cast<const float4*>(&aw[i1]);
    uint2 w0 = make_uint2(pkbf(v0.x,v0.y), pkbf(v0.z,v0.w));
    uint2 w1 = make_uint2(pkbf(v1.x,v1.y), pkbf(v1.z,v1.w));
    *reinterpret_cast<uint2*>(&wbf[i0]) = w0;
    *reinterpret_cast<uint2*>(&wbf[i1]) = w1;
  } else {
    int bid = blockIdx.x - 3200;    // 384 = b16 * ct8 * nt3
    int nt = bid % 3; int ct = (bid/3) & 7; int b = bid / 24;
    int c0 = ct*64, n0 = nt*64;
    int col = tid & 63, r0 = tid >> 6;
    #pragma unroll
    for (int it = 0; it < 16; ++it){
      int r = r0 + it*4;
      Ts[r][col] = x[(b*CC + c0 + r)*NN + n0 + col];
    }
    __syncthreads();
    #pragma unroll
    for (int it = 0; it < 2; ++it){
      int cp = it*256 + tid;
      int nr = cp >> 3, cc8 = (cp & 7)*8;
      uint4v wv;
      wv.x = pkbf(Ts[cc8+0][nr], Ts[cc8+1][nr]);
      wv.y = pkbf(Ts[cc8+2][nr], Ts[cc8+3][nr]);
      wv.z = pkbf(Ts[cc8+4][nr], Ts[cc8+5][nr]);
      wv.w = pkbf(Ts[cc8+6][nr], Ts[cc8+7][nr]);
      *reinterpret_cast<uint4v*>(&xT[((b*NN) + n0 + nr)*CC + c0 + cc8]) = wv;
    }
  }
}

// K1: lin2[b][path*128+cs][n] = sum_c W[cs,c]*x[b,c,n] + per-block partial BN stats
__global__ __launch_bounds__(256) void k1_lin(
    const float* __restrict__ x, const float* __restrict__ wth,
    const float* __restrict__ wph, float* __restrict__ lin2,
    float* __restrict__ spart)
{
  int bid = blockIdx.x;            // 384 = path2 * b16 * ch4 * nt3
  int nt = bid % 3; int ch = (bid/3) & 3; int b = (bid/12) & 15; int path = bid/192;
  int cs0 = ch*32, n0 = nt*64;
  const float* w = path ? wph : wth;
  int tid = threadIdx.x;
  int ty = tid >> 4, tx = tid & 15;
  __shared__ float Xs[32][64];
  __shared__ float Ws[32][36];
  float acc[2][4];
  #pragma unroll
  for (int i=0;i<2;++i)
    #pragma unroll
    for (int j=0;j<4;++j) acc[i][j]=0.f;
  for (int c0 = 0; c0 < CC; c0 += 32){
    __syncthreads();
    {
      int nn4 = (tid & 15)*4, cb = tid >> 4;
      *reinterpret_cast<float4*>(&Xs[cb][nn4]) =
        *reinterpret_cast<const float4*>(&x[(b*CC + c0 + cb)*NN + n0 + nn4]);
      *reinterpret_cast<float4*>(&Xs[cb+16][nn4]) =
        *reinterpret_cast<const float4*>(&x[(b*CC + c0 + cb + 16)*NN + n0 + nn4]);
    }
    {
      int cc = tid & 31, sb = tid >> 5;
      #pragma unroll
      for (int it = 0; it < 4; ++it)
        Ws[cc][sb + it*8] = w[(cs0 + sb + it*8)*CC + c0 + cc];
    }
    __syncthreads();
    #pragma unroll 8
    for (int cc = 0; cc < 32; ++cc){
      float w2[2], x4[4];
      w2[0] = Ws[cc][ty*2]; w2[1] = Ws[cc][ty*2+1];
      *reinterpret_cast<float4*>(x4) = *reinterpret_cast<const float4*>(&Xs[cc][tx*4]);
      #pragma unroll
      for (int i=0;i<2;++i)
        #pragma unroll
        for (int j=0;j<4;++j) acc[i][j] += w2[i]*x4[j];
    }
  }
  #pragma unroll
  for (int r = 0; r < 2; ++r){
    int cs = cs0 + ty*2 + r;
    float4 v = make_float4(acc[r][0],acc[r][1],acc[r][2],acc[r][3]);
    *reinterpret_cast<float4*>(&lin2[(b*256 + path*128 + cs)*NN + n0 + tx*4]) = v;
  }
  #pragma unroll
  for (int r = 0; r < 2; ++r){
    float s = acc[r][0]+acc[r][1]+acc[r][2]+acc[r][3];
    float q = acc[r][0]*acc[r][0]+acc[r][1]*acc[r][1]
            + acc[r][2]*acc[r][2]+acc[r][3]*acc[r][3];
    #pragma unroll
    for (int off=8; off; off>>=1){ s += __shfl_down(s,off,16); q += __shfl_down(q,off,16); }
    if (tx==0){
      int cs2 = path*128 + cs0 + ty*2 + r;
      spart[cs2*48 + b*3 + nt] = s;
      spart[12288 + cs2*48 + b*3 + nt] = q;
    }
  }
}

// K3: raw A/B GEMM; BN scales from spart in-block; BN+relu fused into staging;
// 256 blocks (ih8, 24-wide i tiles); transposed outputs; 8-way partial row sums.
__global__ __launch_bounds__(256) void k3_gemm(
    const float* __restrict__ lin2, const float* __restrict__ spart,
    const float* __restrict__ tg, const float* __restrict__ tbe,
    const float* __restrict__ pg, const float* __restrict__ pbe,
    const float* __restrict__ rw,
    float* __restrict__ p2raw, float* __restrict__ qTraw,
    float* __restrict__ rows8)
{
  int bid = blockIdx.x;            // 256 = path2 * b16 * ih8
  int ih = bid & 7; int b = (bid>>3) & 15; int path = bid >> 7;
  int i0 = ih*24;
  __shared__ float Ls[128][24];
  __shared__ float Ws[64][132];
  __shared__ float sscl[512];
  int tid = threadIdx.x;
  {
    int c2 = tid;
    float s=0.f, q=0.f;
    #pragma unroll 8
    for (int i=0;i<48;++i){ s += spart[c2*48+i]; q += spart[12288+c2*48+i]; }
    float mean = s * (1.f/3072.f);
    float var = q * (1.f/3072.f) - mean*mean;
    int pth = c2 >> 7, c = c2 & 127;
    float g  = pth ? pg[c]  : tg[c];
    float be = pth ? pbe[c] : tbe[c];
    float a = g * rsqrtf(var + EPSF);
    sscl[c2] = a; sscl[256+c2] = be - mean*a;
  }
  __syncthreads();
  #pragma unroll
  for (int it = 0; it < 3; ++it){
    int cp = it*256 + tid;         // 768 float4
    int row = cp / 6, c4 = cp - row*6;
    float a = sscl[path*128 + row], d = sscl[256 + path*128 + row];
    float4 v = *reinterpret_cast<const float4*>(&lin2[(b*256 + path*128 + row)*NN + i0 + c4*4]);
    float4 r;
    r.x = fmaxf(a*v.x + d, 0.f); r.y = fmaxf(a*v.y + d, 0.f);
    r.z = fmaxf(a*v.z + d, 0.f); r.w = fmaxf(a*v.w + d, 0.f);
    *reinterpret_cast<float4*>(&Ls[row][c4*4]) = r;
  }
  #pragma unroll
  for (int it = 0; it < 8; ++it){
    int cp = it*256 + tid;
    int o = cp >> 5, c4 = cp & 31;
    *reinterpret_cast<float4*>(&Ws[o][c4*4]) =
      *reinterpret_cast<const float4*>(&rw[o*CS + c4*4]);
  }
  __syncthreads();
  int oy = tid >> 3, ix = tid & 7;   // oy 0..31 (2 o each), ix 0..7 (3 i each)
  float acc[2][3];
  #pragma unroll
  for (int r=0;r<2;++r)
    #pragma unroll
    for (int e=0;e<3;++e) acc[r][e]=0.f;
  #pragma unroll 4
  for (int c = 0; c < 128; ++c){
    float w2[2], l3[3];
    #pragma unroll
    for (int r=0;r<2;++r) w2[r] = Ws[oy*2+r][c];
    #pragma unroll
    for (int e=0;e<3;++e) l3[e] = Ls[c][ix*3+e];
    #pragma unroll
    for (int r=0;r<2;++r)
      #pragma unroll
      for (int e=0;e<3;++e) acc[r][e] += w2[r]*l3[e];
  }
  float* dst = path ? qTraw : p2raw;
  #pragma unroll
  for (int r=0;r<2;++r)
    #pragma unroll
    for (int e=0;e<3;++e)
      dst[(b*NN + i0 + ix*3 + e)*64 + oy*2 + r] = acc[r][e];
  #pragma unroll
  for (int r=0;r<2;++r){
    float s = acc[r][0]+acc[r][1]+acc[r][2];
    float q = acc[r][0]*acc[r][0]+acc[r][1]*acc[r][1]+acc[r][2]*acc[r][2];
    #pragma unroll
    for (int off=4; off; off>>=1){ s += __shfl_down(s,off,8); q += __shfl_down(q,off,8); }
    if (ix==0){
      int o = oy*2+r;
      int ri = (path*1024 + b*64 + o)*8 + ih;
      rows8[ri] = s; rows8[16384 + ri] = q;
    }
  }
}

// K5: att GEMM, bf16 MFMA. 128x96 tile, ks4, As dbuf + Bs dbuf,
// ONE barrier per rel-iter (genB -> lgkm -> barrier -> stageA -> vmcnt(4) -> MFMA),
// qall preload+prescale, bf16 stores, bijective XCD swizzle.
__global__ __launch_bounds__(256) void k5_mfma(
    const short* __restrict__ wbf, const short* __restrict__ xT,
    const float* __restrict__ p2raw, const float* __restrict__ qTraw,
    const float* __restrict__ rows8,
    const float* __restrict__ rg, const float* __restrict__ rbe,
    unsigned short* __restrict__ attp4)
{
  int swz = (blockIdx.x & 7)*64 + (blockIdx.x >> 3);   // 512 = 8*64, bijective
  int nt = swz & 1, mt = (swz >> 1) & 3, b = (swz >> 3) & 15, ks = swz >> 7;
  int o20 = mt*128, n0 = nt*96;
  int j0 = ks*48;

  int tid = threadIdx.x;
  int w = tid >> 6, lane = tid & 63;
  int wr = w >> 1, wc = w & 1;
  int l15 = lane & 15, l4 = lane >> 4;
  int cq = tid & 7;

  __shared__ __align__(16) short As[2][128*64];   // 32 KB dbuf W tile
  __shared__ __align__(16) short Bs[2][96*64];    // 24 KB dbuf B tile
  __shared__ __align__(16) float qall[48*64];     // 12 KB, prescaled
  __shared__ float srel[128];
  __shared__ float sred[4][5][64];

  // rel-BN scale/shift per o, parallel over 256 threads (4 bb-groups)
  {
    int o = tid & 63, g = tid >> 6;
    float sa=0,sb=0,saq=0,sbq=0,cross=0;
    #pragma unroll
    for (int bb=g*4; bb<g*4+4; ++bb){
      float ra=0, rb=0;
      #pragma unroll
      for (int ih=0; ih<8; ++ih){
        int ia = (bb*64+o)*8 + ih, ib = (1024 + bb*64+o)*8 + ih;
        ra += rows8[ia]; rb += rows8[ib];
        saq += rows8[16384 + ia]; sbq += rows8[16384 + ib];
      }
      sa += ra; sb += rb; cross += ra*rb;
    }
    sred[g][0][o]=sa; sred[g][1][o]=sb; sred[g][2][o]=saq;
    sred[g][3][o]=sbq; sred[g][4][o]=cross;
  }
  // stage all q for j0..j0+47 (contiguous 3072 floats) into LDS
  {
    const float* qsrc = &qTraw[(size_t)(b*NN + j0)*64];
    #pragma unroll
    for (int it=0; it<3; ++it){
      int cp = it*256 + tid;
      gload_lds16(qsrc + cp*4, &qall[cp*4]);
    }
  }
  __syncthreads();
  if (tid < 64){
    int o = tid;
    float sa=0,sb=0,saq=0,sbq=0,cross=0;
    #pragma unroll
    for (int g=0; g<4; ++g){
      sa += sred[g][0][o]; sb += sred[g][1][o]; saq += sred[g][2][o];
      sbq += sred[g][3][o]; cross += sred[g][4][o];
    }
    float mean = (sa - sb) * (1.f/3072.f);
    float e2 = (saq + sbq) * (1.f/3072.f) - cross * (2.f/589824.f);
    float var = e2 - mean*mean;
    float s = rg[o] * rsqrtf(var + EPSF);
    srel[o] = s;
    srel[64+o] = rbe[o] - s*mean;
  }
  __syncthreads();

  // register-resident scaled p: pr[it][k] at n = n0 + it*32+(tid>>3), o = cq*8+k
  float pr[3][8];
  {
    float sc8[8], sh8[8];
    #pragma unroll
    for (int k=0;k<8;++k){ sc8[k] = srel[cq*8+k]; sh8[k] = srel[64+cq*8+k]; }
    #pragma unroll
    for (int it=0; it<3; ++it){
      int n = it*32 + (tid >> 3);
      const float* pp = &p2raw[(size_t)((b*NN) + n0 + n)*64 + cq*8];
      float4 u0 = *reinterpret_cast<const float4*>(pp);
      float4 u1 = *reinterpret_cast<const float4*>(pp+4);
      pr[it][0]=sc8[0]*u0.x+sh8[0]; pr[it][1]=sc8[1]*u0.y+sh8[1];
      pr[it][2]=sc8[2]*u0.z+sh8[2]; pr[it][3]=sc8[3]*u0.w+sh8[3];
      pr[it][4]=sc8[4]*u1.x+sh8[4]; pr[it][5]=sc8[5]*u1.y+sh8[5];
      pr[it][6]=sc8[6]*u1.z+sh8[6]; pr[it][7]=sc8[7]*u1.w+sh8[7];
    }
  }

  auto stageA = [&](int buf, int colbase){
    #pragma unroll
    for (int it=0; it<4; ++it){
      int cp = w*256 + it*64 + lane;
      int row = cp >> 3, c = (cp & 7) ^ (row & 7);
      gload_lds16(&wbf[(o20 + row)*12800 + colbase + c*8],
                  &As[buf][(w*256 + it*64)*8]);
    }
  };
  auto stageBx = [&](int buf, int colbase){
    #pragma unroll
    for (int it=0; it<3; ++it){
      int cp = w*192 + it*64 + lane;
      int row = cp >> 3, c = (cp & 7) ^ (row & 7);
      gload_lds16(&xT[(size_t)((b*NN) + n0 + row)*CC + colbase + c*8],
                  &Bs[buf][(w*192 + it*64)*8]);
    }
  };

  f32x4 acc[4][3];
  #pragma unroll
  for (int mi=0;mi<4;++mi)
    #pragma unroll
    for (int ni=0;ni<3;++ni) acc[mi][ni] = (f32x4){0.f,0.f,0.f,0.f};

  auto mfma_phase = [&](int abuf, int bbuf){
    __builtin_amdgcn_s_setprio(1);
    #pragma unroll
    for (int s=0; s<2; ++s){
      short8 av[4], bv[3];
      int c = s*4 + l4;
      #pragma unroll
      for (int mi=0; mi<4; ++mi){
        int row = wr*64 + mi*16 + l15;
        av[mi] = *reinterpret_cast<const short8*>(&As[abuf][row*64 + ((c ^ (row&7))<<3)]);
      }
      #pragma unroll
      for (int ni=0; ni<3; ++ni){
        int rown = wc*48 + ni*16 + l15;
        bv[ni] = *reinterpret_cast<const short8*>(&Bs[bbuf][rown*64 + ((c ^ (rown&7))<<3)]);
      }
      #pragma unroll
      for (int mi=0; mi<4; ++mi)
        #pragma unroll
        for (int ni=0; ni<3; ++ni)
          acc[mi][ni] = __builtin_amdgcn_mfma_f32_16x16x32_bf16(av[mi], bv[ni], acc[mi][ni], 0, 0, 0);
    }
    __builtin_amdgcn_s_setprio(0);
  };

  // ---- x-part: 2 k-tiles (128 channels at ks*128), plain barriers, As[0] ----
  #pragma unroll
  for (int kt = 0; kt < 2; ++kt){
    __syncthreads();               // kt=0: also drains qall gloads (vmcnt(0))
    stageA(0, ks*128 + kt*64);
    stageBx(kt, ks*128 + kt*64);
    if (kt == 0){
      #pragma unroll
      for (int it=0; it<12; ++it){
        int i = it*256 + tid;
        qall[i] *= srel[i & 63];
      }
    }
    __syncthreads();
    mfma_phase(0, kt);
  }

  // ---- rel part: 48 j-iters, As+Bs double-buffered, ONE barrier per iter ----
  __syncthreads();                  // x-MFMA done reading As[0]/Bs[0..1]
  stageA(0, 512 + j0*64);           // prologue stage for kt=0, 4 gloads in flight
  for (int kt = 0; kt < 48; ++kt){
    int cur = kt & 1;
    // genB into Bs[cur] (laggard waves may still be in MFMA(kt-1) reading Bs[cur^1])
    {
      const float* qq = &qall[kt*64];
      float4 qa = *reinterpret_cast<const float4*>(&qq[cq*8]);
      float4 qb = *reinterpret_cast<const float4*>(&qq[cq*8+4]);
      #pragma unroll
      for (int it=0; it<3; ++it){
        float r0 = fmaxf(pr[it][0]-qa.x, 0.f);
        float r1 = fmaxf(pr[it][1]-qa.y, 0.f);
        float r2 = fmaxf(pr[it][2]-qa.z, 0.f);
        float r3 = fmaxf(pr[it][3]-qa.w, 0.f);
        float r4 = fmaxf(pr[it][4]-qb.x, 0.f);
        float r5 = fmaxf(pr[it][5]-qb.y, 0.f);
        float r6 = fmaxf(pr[it][6]-qb.z, 0.f);
        float r7 = fmaxf(pr[it][7]-qb.w, 0.f);
        uint4v wv;
        wv.x = pkbf(r0,r1); wv.y = pkbf(r2,r3);
        wv.z = pkbf(r4,r5); wv.w = pkbf(r6,r7);
        int n = it*32 + (tid >> 3);
        *reinterpret_cast<uint4v*>(&Bs[cur][n*64 + ((cq ^ (n&7))<<3)]) = wv;
      }
    }
    asm volatile("s_waitcnt lgkmcnt(0)" ::: "memory");   // own genB writes landed
    __builtin_amdgcn_s_barrier();                        // all waves: MFMA(kt-1) + genB(kt) done
    if (kt < 47){
      stageA(cur^1, 512 + (j0 + kt + 1)*64);             // safe: post-barrier
      asm volatile("s_waitcnt vmcnt(4)" ::: "memory");   // As[cur] (older 4) ready
    } else {
      asm volatile("s_waitcnt vmcnt(0)" ::: "memory");
    }
    __builtin_amdgcn_sched_barrier(0);
    mfma_phase(cur, cur);
    // no trailing barrier: next iter's genB targets Bs[cur^1]
  }

  // bf16 partial stores: each (b,o2,n) written by exactly one block per ks
  unsigned short* dst = attp4 + (size_t)ks*PART;
  #pragma unroll
  for (int mi=0; mi<4; ++mi){
    #pragma unroll
    for (int r=0; r<4; ++r){
      int o2 = o20 + wr*64 + mi*16 + l4*4 + r;
      #pragma unroll
      for (int ni=0; ni<3; ++ni){
        int n = n0 + wc*48 + ni*16 + l15;
        dst[(b*CC + o2)*NN + n] = (unsigned short)pkbf(acc[mi][ni][r], 0.f);
      }
    }
  }
}

// K67: per-channel: sum 4 bf16 partials (uint pair loads) -> BN stats -> sigmoid -> out
__global__ __launch_bounds__(256) void k67(
    const unsigned short* __restrict__ p4, const float* __restrict__ x,
    const float* __restrict__ g, const float* __restrict__ be,
    float* __restrict__ out)
{
  int o2 = blockIdx.x;   // 512
  int tid = threadIdx.x;
  int b = tid >> 4, nl = tid & 15;
  float v[12], xv[12];
  float s=0.f, q=0.f;
  #pragma unroll
  for (int it=0; it<6; ++it){
    int n = nl*2 + it*32;
    int idx = (b*CC + o2)*NN + n;   // even -> uint-aligned
    float t0=0.f, t1=0.f;
    #pragma unroll
    for (int p=0; p<4; ++p){
      unsigned u = *reinterpret_cast<const unsigned*>(&p4[(size_t)p*PART + idx]);
      t0 += __uint_as_float(u << 16);
      t1 += __uint_as_float(u & 0xffff0000u);
    }
    float2 xu = *reinterpret_cast<const float2*>(&x[idx]);
    v[it*2] = t0; v[it*2+1] = t1;
    xv[it*2] = xu.x; xv[it*2+1] = xu.y;
    s += t0 + t1; q += t0*t0 + t1*t1;
  }
  __shared__ float rs[4], rq[4], ad[2];
  #pragma unroll
  for (int off=32; off; off>>=1){ s += __shfl_down(s,off); q += __shfl_down(q,off); }
  int w = tid >> 6;
  if ((tid & 63)==0){ rs[w]=s; rq[w]=q; }
  __syncthreads();
  if (tid==0){
    s = rs[0]+rs[1]+rs[2]+rs[3]; q = rq[0]+rq[1]+rq[2]+rq[3];
    float mean = s * (1.f/3072.f);
    float var = q * (1.f/3072.f) - mean*mean;
    float a = g[o2] * rsqrtf(var + EPSF);
    ad[0] = a; ad[1] = be[o2] - mean*a;
  }
  __syncthreads();
  float a = ad[0], d = ad[1];
  float sf=0.f, ss=0.f;
  #pragma unroll
  for (int it=0; it<12; ++it){
    float sig = 1.f/(1.f + expf(-(a*v[it] + d)));
    sf += sig * xv[it]; ss += sig;
  }
  #pragma unroll
  for (int off=8; off; off>>=1){ sf += __shfl_down(sf,off,16); ss += __shfl_down(ss,off,16); }
  if (nl==0) out[b*CC + o2] = sf/ss;
}

extern "C" void kernel_launch(void* const* d_in, const int* in_sizes, int n_in,
                              void* d_out, int out_size, void* d_ws, size_t ws_size,
                              hipStream_t stream)
{
  const float* inputs  = (const float*)d_in[0];
  const float* theta_w = (const float*)d_in[2];
  const float* theta_g = (const float*)d_in[4];
  const float* theta_be= (const float*)d_in[5];
  const float* phi_w   = (const float*)d_in[6];
  const float* phi_g   = (const float*)d_in[8];
  const float* phi_be  = (const float*)d_in[9];
  const float* re_w    = (const float*)d_in[10];
  const float* re_g    = (const float*)d_in[12];
  const float* re_be   = (const float*)d_in[13];
  const float* att_w   = (const float*)d_in[14];
  const float* att_g   = (const float*)d_in[16];
  const float* att_be  = (const float*)d_in[17];

  float* ws = (float*)d_ws;
  float* lin2  = ws + OFF_LIN2;
  float* p2raw = ws + OFF_P2;
  float* qTraw = ws + OFF_QT;
  unsigned short* attp4 = (unsigned short*)(ws + OFF_ATTP4);
  short* wbf   = (short*)(ws + OFF_WBF);
  short* xT    = (short*)(ws + OFF_XT);
  float* rows8 = ws + OFF_ROWS;
  float* spart = ws + OFF_SPART;

  kconvxt<<<3584, 256, 0, stream>>>(att_w, inputs, wbf, xT);
  k1_lin<<<384, 256, 0, stream>>>(inputs, theta_w, phi_w, lin2, spart);
  k3_gemm<<<256, 256, 0, stream>>>(lin2, spart, theta_g, theta_be, phi_g, phi_be,
                                   re_w, p2raw, qTraw, rows8);
  k5_mfma<<<512, 256, 0, stream>>>(wbf, xT, p2raw, qTraw, rows8, re_g, re_be, attp4);
  k67<<<512, 256, 0, stream>>>(attp4, inputs, att_g, att_be, (float*)d_out);
}

// Round 18
// 115.789 us; speedup vs baseline: 1.0553x; 1.0553x over previous
//
#include <hip/hip_runtime.h>

#define BB 16
#define CC 512
#define NN 192
#define CS 128
#define CR 64
#define EPSF 1e-5f
#define PART (BB*CC*NN)                    // 1572864

typedef __attribute__((ext_vector_type(8))) short short8;
typedef __attribute__((ext_vector_type(4))) float f32x4;
typedef __attribute__((ext_vector_type(4))) unsigned int uint4v;

// ---------------- workspace layout (float units) ----------------
#define OFF_LIN2  0                        // 786432
#define OFF_P2    786432                   // 196608  p2raw[b][i][o] (unscaled)
#define OFF_QT    983040                   // 196608  qTraw[b][j][o] (unscaled)
#define OFF_ATTP4 1179648                  // 4 bf16 partials = 4*PART ushort = 2*PART floats
#define OFF_WBF   7471104                  // short[512*12800] = 3276800 floats
#define OFF_XT    10747904                 // short[16*192*512] = 786432 floats
#define OFF_ROWS  11534336                 // 32768 (sum 16384 + sq 16384), ih8
#define OFF_SPART 11567104                 // 24576

__device__ __forceinline__ unsigned pkbf(float a, float b){
  unsigned r; asm("v_cvt_pk_bf16_f32 %0, %1, %2" : "=v"(r) : "v"(a), "v"(b)); return r;
}

__device__ __forceinline__ void gload_lds16(const void* g, void* l){
  __builtin_amdgcn_global_load_lds(
      (const __attribute__((address_space(1))) unsigned int*)g,
      (__attribute__((address_space(3))) unsigned int*)l, 16, 0, 0);
}

// KCONVXT: att_w -> bf16 wbf (blocks 0..3199, fully coalesced);
//          inputs -> xT bf16 [b][n][c] (3200..3583)
__global__ __launch_bounds__(256) void kconvxt(
    const float* __restrict__ aw, const float* __restrict__ x,
    short* __restrict__ wbf, short* __restrict__ xT)
{
  __shared__ float Ts[64][65];
  int tid = threadIdx.x;
  if (blockIdx.x < 3200) {
    int base = blockIdx.x * 2048;
    int i0 = base + tid*4;
    int i1 = base + 1024 + tid*4;
    float4 v0 = *reinterpret_cast<const float4*>(&aw[i0]);
    float4 v1 = *reinterpret_cast<const float4*>(&aw[i1]);
    uint2 w0 = make_uint2(pkbf(v0.x,v0.y), pkbf(v0.z,v0.w));
    uint2 w1 = make_uint2(pkbf(v1.x,v1.y), pkbf(v1.z,v1.w));
    *reinterpret_cast<uint2*>(&wbf[i0]) = w0;
    *reinterpret_cast<uint2*>(&wbf[i1]) = w1;
  } else {
    int bid = blockIdx.x - 3200;    // 384 = b16 * ct8 * nt3
    int nt = bid % 3; int ct = (bid/3) & 7; int b = bid / 24;
    int c0 = ct*64, n0 = nt*64;
    int col = tid & 63, r0 = tid >> 6;
    #pragma unroll
    for (int it = 0; it < 16; ++it){
      int r = r0 + it*4;
      Ts[r][col] = x[(b*CC + c0 + r)*NN + n0 + col];
    }
    __syncthreads();
    #pragma unroll
    for (int it = 0; it < 2; ++it){
      int cp = it*256 + tid;
      int nr = cp >> 3, cc8 = (cp & 7)*8;
      uint4v wv;
      wv.x = pkbf(Ts[cc8+0][nr], Ts[cc8+1][nr]);
      wv.y = pkbf(Ts[cc8+2][nr], Ts[cc8+3][nr]);
      wv.z = pkbf(Ts[cc8+4][nr], Ts[cc8+5][nr]);
      wv.w = pkbf(Ts[cc8+6][nr], Ts[cc8+7][nr]);
      *reinterpret_cast<uint4v*>(&xT[((b*NN) + n0 + nr)*CC + c0 + cc8]) = wv;
    }
  }
}

// K1: lin2[b][path*128+cs][n] = sum_c W[cs,c]*x[b,c,n] + per-block partial BN stats
__global__ __launch_bounds__(256) void k1_lin(
    const float* __restrict__ x, const float* __restrict__ wth,
    const float* __restrict__ wph, float* __restrict__ lin2,
    float* __restrict__ spart)
{
  int bid = blockIdx.x;            // 384 = path2 * b16 * ch4 * nt3
  int nt = bid % 3; int ch = (bid/3) & 3; int b = (bid/12) & 15; int path = bid/192;
  int cs0 = ch*32, n0 = nt*64;
  const float* w = path ? wph : wth;
  int tid = threadIdx.x;
  int ty = tid >> 4, tx = tid & 15;
  __shared__ float Xs[32][64];
  __shared__ float Ws[32][36];
  float acc[2][4];
  #pragma unroll
  for (int i=0;i<2;++i)
    #pragma unroll
    for (int j=0;j<4;++j) acc[i][j]=0.f;
  for (int c0 = 0; c0 < CC; c0 += 32){
    __syncthreads();
    {
      int nn4 = (tid & 15)*4, cb = tid >> 4;
      *reinterpret_cast<float4*>(&Xs[cb][nn4]) =
        *reinterpret_cast<const float4*>(&x[(b*CC + c0 + cb)*NN + n0 + nn4]);
      *reinterpret_cast<float4*>(&Xs[cb+16][nn4]) =
        *reinterpret_cast<const float4*>(&x[(b*CC + c0 + cb + 16)*NN + n0 + nn4]);
    }
    {
      int cc = tid & 31, sb = tid >> 5;
      #pragma unroll
      for (int it = 0; it < 4; ++it)
        Ws[cc][sb + it*8] = w[(cs0 + sb + it*8)*CC + c0 + cc];
    }
    __syncthreads();
    #pragma unroll 8
    for (int cc = 0; cc < 32; ++cc){
      float w2[2], x4[4];
      w2[0] = Ws[cc][ty*2]; w2[1] = Ws[cc][ty*2+1];
      *reinterpret_cast<float4*>(x4) = *reinterpret_cast<const float4*>(&Xs[cc][tx*4]);
      #pragma unroll
      for (int i=0;i<2;++i)
        #pragma unroll
        for (int j=0;j<4;++j) acc[i][j] += w2[i]*x4[j];
    }
  }
  #pragma unroll
  for (int r = 0; r < 2; ++r){
    int cs = cs0 + ty*2 + r;
    float4 v = make_float4(acc[r][0],acc[r][1],acc[r][2],acc[r][3]);
    *reinterpret_cast<float4*>(&lin2[(b*256 + path*128 + cs)*NN + n0 + tx*4]) = v;
  }
  #pragma unroll
  for (int r = 0; r < 2; ++r){
    float s = acc[r][0]+acc[r][1]+acc[r][2]+acc[r][3];
    float q = acc[r][0]*acc[r][0]+acc[r][1]*acc[r][1]
            + acc[r][2]*acc[r][2]+acc[r][3]*acc[r][3];
    #pragma unroll
    for (int off=8; off; off>>=1){ s += __shfl_down(s,off,16); q += __shfl_down(q,off,16); }
    if (tx==0){
      int cs2 = path*128 + cs0 + ty*2 + r;
      spart[cs2*48 + b*3 + nt] = s;
      spart[12288 + cs2*48 + b*3 + nt] = q;
    }
  }
}

// K3: raw A/B GEMM; BN scales from spart in-block; BN+relu fused into staging;
// 256 blocks (ih8, 24-wide i tiles); transposed outputs; 8-way partial row sums.
__global__ __launch_bounds__(256) void k3_gemm(
    const float* __restrict__ lin2, const float* __restrict__ spart,
    const float* __restrict__ tg, const float* __restrict__ tbe,
    const float* __restrict__ pg, const float* __restrict__ pbe,
    const float* __restrict__ rw,
    float* __restrict__ p2raw, float* __restrict__ qTraw,
    float* __restrict__ rows8)
{
  int bid = blockIdx.x;            // 256 = path2 * b16 * ih8
  int ih = bid & 7; int b = (bid>>3) & 15; int path = bid >> 7;
  int i0 = ih*24;
  __shared__ float Ls[128][24];
  __shared__ float Ws[64][132];
  __shared__ float sscl[512];
  int tid = threadIdx.x;
  {
    int c2 = tid;
    float s=0.f, q=0.f;
    #pragma unroll 8
    for (int i=0;i<48;++i){ s += spart[c2*48+i]; q += spart[12288+c2*48+i]; }
    float mean = s * (1.f/3072.f);
    float var = q * (1.f/3072.f) - mean*mean;
    int pth = c2 >> 7, c = c2 & 127;
    float g  = pth ? pg[c]  : tg[c];
    float be = pth ? pbe[c] : tbe[c];
    float a = g * rsqrtf(var + EPSF);
    sscl[c2] = a; sscl[256+c2] = be - mean*a;
  }
  __syncthreads();
  #pragma unroll
  for (int it = 0; it < 3; ++it){
    int cp = it*256 + tid;         // 768 float4
    int row = cp / 6, c4 = cp - row*6;
    float a = sscl[path*128 + row], d = sscl[256 + path*128 + row];
    float4 v = *reinterpret_cast<const float4*>(&lin2[(b*256 + path*128 + row)*NN + i0 + c4*4]);
    float4 r;
    r.x = fmaxf(a*v.x + d, 0.f); r.y = fmaxf(a*v.y + d, 0.f);
    r.z = fmaxf(a*v.z + d, 0.f); r.w = fmaxf(a*v.w + d, 0.f);
    *reinterpret_cast<float4*>(&Ls[row][c4*4]) = r;
  }
  #pragma unroll
  for (int it = 0; it < 8; ++it){
    int cp = it*256 + tid;
    int o = cp >> 5, c4 = cp & 31;
    *reinterpret_cast<float4*>(&Ws[o][c4*4]) =
      *reinterpret_cast<const float4*>(&rw[o*CS + c4*4]);
  }
  __syncthreads();
  int oy = tid >> 3, ix = tid & 7;   // oy 0..31 (2 o each), ix 0..7 (3 i each)
  float acc[2][3];
  #pragma unroll
  for (int r=0;r<2;++r)
    #pragma unroll
    for (int e=0;e<3;++e) acc[r][e]=0.f;
  #pragma unroll 4
  for (int c = 0; c < 128; ++c){
    float w2[2], l3[3];
    #pragma unroll
    for (int r=0;r<2;++r) w2[r] = Ws[oy*2+r][c];
    #pragma unroll
    for (int e=0;e<3;++e) l3[e] = Ls[c][ix*3+e];
    #pragma unroll
    for (int r=0;r<2;++r)
      #pragma unroll
      for (int e=0;e<3;++e) acc[r][e] += w2[r]*l3[e];
  }
  float* dst = path ? qTraw : p2raw;
  #pragma unroll
  for (int r=0;r<2;++r)
    #pragma unroll
    for (int e=0;e<3;++e)
      dst[(b*NN + i0 + ix*3 + e)*64 + oy*2 + r] = acc[r][e];
  #pragma unroll
  for (int r=0;r<2;++r){
    float s = acc[r][0]+acc[r][1]+acc[r][2];
    float q = acc[r][0]*acc[r][0]+acc[r][1]*acc[r][1]+acc[r][2]*acc[r][2];
    #pragma unroll
    for (int off=4; off; off>>=1){ s += __shfl_down(s,off,8); q += __shfl_down(q,off,8); }
    if (ix==0){
      int o = oy*2+r;
      int ri = (path*1024 + b*64 + o)*8 + ih;
      rows8[ri] = s; rows8[16384 + ri] = q;
    }
  }
}

// K5: att GEMM, bf16 MFMA. r11/r13-proven: 128x96 tile, ks4, 2 x-tiles +
// 48 rel-iters, As dbuf + counted vmcnt(4), qall preload+prescale, bf16 stores,
// bijective XCD swizzle.
__global__ __launch_bounds__(256) void k5_mfma(
    const short* __restrict__ wbf, const short* __restrict__ xT,
    const float* __restrict__ p2raw, const float* __restrict__ qTraw,
    const float* __restrict__ rows8,
    const float* __restrict__ rg, const float* __restrict__ rbe,
    unsigned short* __restrict__ attp4)
{
  int swz = (blockIdx.x & 7)*64 + (blockIdx.x >> 3);   // 512 = 8*64, bijective
  int nt = swz & 1, mt = (swz >> 1) & 3, b = (swz >> 3) & 15, ks = swz >> 7;
  int o20 = mt*128, n0 = nt*96;
  int j0 = ks*48;

  int tid = threadIdx.x;
  int w = tid >> 6, lane = tid & 63;
  int wr = w >> 1, wc = w & 1;
  int l15 = lane & 15, l4 = lane >> 4;
  int cq = tid & 7;

  __shared__ __align__(16) short As[2][128*64];   // 32 KB double-buffered W tile
  __shared__ __align__(16) short Bs[96*64];       // 12 KB
  __shared__ __align__(16) float qall[48*64];     // 12 KB: all q for this ks, prescaled
  __shared__ float srel[128];
  __shared__ float sred[4][5][64];

  // rel-BN scale/shift per o, parallel over 256 threads (4 bb-groups)
  {
    int o = tid & 63, g = tid >> 6;
    float sa=0,sb=0,saq=0,sbq=0,cross=0;
    #pragma unroll
    for (int bb=g*4; bb<g*4+4; ++bb){
      float ra=0, rb=0;
      #pragma unroll
      for (int ih=0; ih<8; ++ih){
        int ia = (bb*64+o)*8 + ih, ib = (1024 + bb*64+o)*8 + ih;
        ra += rows8[ia]; rb += rows8[ib];
        saq += rows8[16384 + ia]; sbq += rows8[16384 + ib];
      }
      sa += ra; sb += rb; cross += ra*rb;
    }
    sred[g][0][o]=sa; sred[g][1][o]=sb; sred[g][2][o]=saq;
    sred[g][3][o]=sbq; sred[g][4][o]=cross;
  }
  // stage all q for j0..j0+47 (contiguous 3072 floats) into LDS
  {
    const float* qsrc = &qTraw[(size_t)(b*NN + j0)*64];
    #pragma unroll
    for (int it=0; it<3; ++it){
      int cp = it*256 + tid;
      gload_lds16(qsrc + cp*4, &qall[cp*4]);
    }
  }
  __syncthreads();
  if (tid < 64){
    int o = tid;
    float sa=0,sb=0,saq=0,sbq=0,cross=0;
    #pragma unroll
    for (int g=0; g<4; ++g){
      sa += sred[g][0][o]; sb += sred[g][1][o]; saq += sred[g][2][o];
      sbq += sred[g][3][o]; cross += sred[g][4][o];
    }
    float mean = (sa - sb) * (1.f/3072.f);
    float e2 = (saq + sbq) * (1.f/3072.f) - cross * (2.f/589824.f);
    float var = e2 - mean*mean;
    float s = rg[o] * rsqrtf(var + EPSF);
    srel[o] = s;
    srel[64+o] = rbe[o] - s*mean;
  }
  __syncthreads();

  // register-resident scaled p: pr[it][k] at n = n0 + it*32+(tid>>3), o = cq*8+k
  float pr[3][8];
  {
    float sc8[8], sh8[8];
    #pragma unroll
    for (int k=0;k<8;++k){ sc8[k] = srel[cq*8+k]; sh8[k] = srel[64+cq*8+k]; }
    #pragma unroll
    for (int it=0; it<3; ++it){
      int n = it*32 + (tid >> 3);
      const float* pp = &p2raw[(size_t)((b*NN) + n0 + n)*64 + cq*8];
      float4 u0 = *reinterpret_cast<const float4*>(pp);
      float4 u1 = *reinterpret_cast<const float4*>(pp+4);
      pr[it][0]=sc8[0]*u0.x+sh8[0]; pr[it][1]=sc8[1]*u0.y+sh8[1];
      pr[it][2]=sc8[2]*u0.z+sh8[2]; pr[it][3]=sc8[3]*u0.w+sh8[3];
      pr[it][4]=sc8[4]*u1.x+sh8[4]; pr[it][5]=sc8[5]*u1.y+sh8[5];
      pr[it][6]=sc8[6]*u1.z+sh8[6]; pr[it][7]=sc8[7]*u1.w+sh8[7];
    }
  }

  auto stageA = [&](int buf, int colbase){
    #pragma unroll
    for (int it=0; it<4; ++it){
      int cp = w*256 + it*64 + lane;
      int row = cp >> 3, c = (cp & 7) ^ (row & 7);
      gload_lds16(&wbf[(o20 + row)*12800 + colbase + c*8],
                  &As[buf][(w*256 + it*64)*8]);
    }
  };
  auto stageBx = [&](int colbase){
    #pragma unroll
    for (int it=0; it<3; ++it){
      int cp = w*192 + it*64 + lane;
      int row = cp >> 3, c = (cp & 7) ^ (row & 7);
      gload_lds16(&xT[(size_t)((b*NN) + n0 + row)*CC + colbase + c*8],
                  &Bs[(w*192 + it*64)*8]);
    }
  };

  f32x4 acc[4][3];
  #pragma unroll
  for (int mi=0;mi<4;++mi)
    #pragma unroll
    for (int ni=0;ni<3;++ni) acc[mi][ni] = (f32x4){0.f,0.f,0.f,0.f};

  auto mfma_phase = [&](int buf){
    __builtin_amdgcn_s_setprio(1);
    #pragma unroll
    for (int s=0; s<2; ++s){
      short8 av[4], bv[3];
      int c = s*4 + l4;
      #pragma unroll
      for (int mi=0; mi<4; ++mi){
        int row = wr*64 + mi*16 + l15;
        av[mi] = *reinterpret_cast<const short8*>(&As[buf][row*64 + ((c ^ (row&7))<<3)]);
      }
      #pragma unroll
      for (int ni=0; ni<3; ++ni){
        int rown = wc*48 + ni*16 + l15;
        bv[ni] = *reinterpret_cast<const short8*>(&Bs[rown*64 + ((c ^ (rown&7))<<3)]);
      }
      #pragma unroll
      for (int mi=0; mi<4; ++mi)
        #pragma unroll
        for (int ni=0; ni<3; ++ni)
          acc[mi][ni] = __builtin_amdgcn_mfma_f32_16x16x32_bf16(av[mi], bv[ni], acc[mi][ni], 0, 0, 0);
    }
    __builtin_amdgcn_s_setprio(0);
  };

  // ---- x-part: 2 k-tiles (128 channels at ks*128), plain barriers, As[0] ----
  #pragma unroll
  for (int kt = 0; kt < 2; ++kt){
    __syncthreads();               // kt=0: also drains qall gloads (vmcnt(0))
    stageA(0, ks*128 + kt*64);
    stageBx(ks*128 + kt*64);
    if (kt == 0){
      #pragma unroll
      for (int it=0; it<12; ++it){
        int i = it*256 + tid;
        qall[i] *= srel[i & 63];
      }
    }
    __syncthreads();
    mfma_phase(0);
  }

  // ---- rel part: 48 j-iters, As double-buffered, counted vmcnt ----
  __syncthreads();                  // x-MFMA done reading As[0]/Bs
  stageA(0, 512 + j0*64);           // prologue stage, 4 gloads in flight
  for (int kt = 0; kt < 48; ++kt){
    int cur = kt & 1;
    if (kt < 47) stageA(cur^1, 512 + (j0 + kt + 1)*64);
    {
      const float* qq = &qall[kt*64];
      float4 qa = *reinterpret_cast<const float4*>(&qq[cq*8]);
      float4 qb = *reinterpret_cast<const float4*>(&qq[cq*8+4]);
      #pragma unroll
      for (int it=0; it<3; ++it){
        float r0 = fmaxf(pr[it][0]-qa.x, 0.f);
        float r1 = fmaxf(pr[it][1]-qa.y, 0.f);
        float r2 = fmaxf(pr[it][2]-qa.z, 0.f);
        float r3 = fmaxf(pr[it][3]-qa.w, 0.f);
        float r4 = fmaxf(pr[it][4]-qb.x, 0.f);
        float r5 = fmaxf(pr[it][5]-qb.y, 0.f);
        float r6 = fmaxf(pr[it][6]-qb.z, 0.f);
        float r7 = fmaxf(pr[it][7]-qb.w, 0.f);
        uint4v wv;
        wv.x = pkbf(r0,r1); wv.y = pkbf(r2,r3);
        wv.z = pkbf(r4,r5); wv.w = pkbf(r6,r7);
        int n = it*32 + (tid >> 3);
        *reinterpret_cast<uint4v*>(&Bs[n*64 + ((cq ^ (n&7))<<3)]) = wv;
      }
    }
    if (kt < 47) asm volatile("s_waitcnt vmcnt(4) lgkmcnt(0)" ::: "memory");
    else         asm volatile("s_waitcnt vmcnt(0) lgkmcnt(0)" ::: "memory");
    __builtin_amdgcn_sched_barrier(0);
    __builtin_amdgcn_s_barrier();
    mfma_phase(cur);
    __builtin_amdgcn_s_barrier();
  }

  // bf16 partial stores: each (b,o2,n) written by exactly one block per ks
  unsigned short* dst = attp4 + (size_t)ks*PART;
  #pragma unroll
  for (int mi=0; mi<4; ++mi){
    #pragma unroll
    for (int r=0; r<4; ++r){
      int o2 = o20 + wr*64 + mi*16 + l4*4 + r;
      #pragma unroll
      for (int ni=0; ni<3; ++ni){
        int n = n0 + wc*48 + ni*16 + l15;
        dst[(b*CC + o2)*NN + n] = (unsigned short)pkbf(acc[mi][ni][r], 0.f);
      }
    }
  }
}

// K67: per-channel: sum 4 bf16 partials (uint pair loads) -> BN stats -> sigmoid -> out
__global__ __launch_bounds__(256) void k67(
    const unsigned short* __restrict__ p4, const float* __restrict__ x,
    const float* __restrict__ g, const float* __restrict__ be,
    float* __restrict__ out)
{
  int o2 = blockIdx.x;   // 512
  int tid = threadIdx.x;
  int b = tid >> 4, nl = tid & 15;
  float v[12], xv[12];
  float s=0.f, q=0.f;
  #pragma unroll
  for (int it=0; it<6; ++it){
    int n = nl*2 + it*32;
    int idx = (b*CC + o2)*NN + n;   // even -> uint-aligned
    float t0=0.f, t1=0.f;
    #pragma unroll
    for (int p=0; p<4; ++p){
      unsigned u = *reinterpret_cast<const unsigned*>(&p4[(size_t)p*PART + idx]);
      t0 += __uint_as_float(u << 16);
      t1 += __uint_as_float(u & 0xffff0000u);
    }
    float2 xu = *reinterpret_cast<const float2*>(&x[idx]);
    v[it*2] = t0; v[it*2+1] = t1;
    xv[it*2] = xu.x; xv[it*2+1] = xu.y;
    s += t0 + t1; q += t0*t0 + t1*t1;
  }
  __shared__ float rs[4], rq[4], ad[2];
  #pragma unroll
  for (int off=32; off; off>>=1){ s += __shfl_down(s,off); q += __shfl_down(q,off); }
  int w = tid >> 6;
  if ((tid & 63)==0){ rs[w]=s; rq[w]=q; }
  __syncthreads();
  if (tid==0){
    s = rs[0]+rs[1]+rs[2]+rs[3]; q = rq[0]+rq[1]+rq[2]+rq[3];
    float mean = s * (1.f/3072.f);
    float var = q * (1.f/3072.f) - mean*mean;
    float a = g[o2] * rsqrtf(var + EPSF);
    ad[0] = a; ad[1] = be[o2] - mean*a;
  }
  __syncthreads();
  float a = ad[0], d = ad[1];
  float sf=0.f, ss=0.f;
  #pragma unroll
  for (int it=0; it<12; ++it){
    float sig = 1.f/(1.f + expf(-(a*v[it] + d)));
    sf += sig * xv[it]; ss += sig;
  }
  #pragma unroll
  for (int off=8; off; off>>=1){ sf += __shfl_down(sf,off,16); ss += __shfl_down(ss,off,16); }
  if (nl==0) out[b*CC + o2] = sf/ss;
}

extern "C" void kernel_launch(void* const* d_in, const int* in_sizes, int n_in,
                              void* d_out, int out_size, void* d_ws, size_t ws_size,
                              hipStream_t stream)
{
  const float* inputs  = (const float*)d_in[0];
  const float* theta_w = (const float*)d_in[2];
  const float* theta_g = (const float*)d_in[4];
  const float* theta_be= (const float*)d_in[5];
  const float* phi_w   = (const float*)d_in[6];
  const float* phi_g   = (const float*)d_in[8];
  const float* phi_be  = (const float*)d_in[9];
  const float* re_w    = (const float*)d_in[10];
  const float* re_g    = (const float*)d_in[12];
  const float* re_be   = (const float*)d_in[13];
  const float* att_w   = (const float*)d_in[14];
  const float* att_g   = (const float*)d_in[16];
  const float* att_be  = (const float*)d_in[17];

  float* ws = (float*)d_ws;
  float* lin2  = ws + OFF_LIN2;
  float* p2raw = ws + OFF_P2;
  float* qTraw = ws + OFF_QT;
  unsigned short* attp4 = (unsigned short*)(ws + OFF_ATTP4);
  short* wbf   = (short*)(ws + OFF_WBF);
  short* xT    = (short*)(ws + OFF_XT);
  float* rows8 = ws + OFF_ROWS;
  float* spart = ws + OFF_SPART;

  kconvxt<<<3584, 256, 0, stream>>>(att_w, inputs, wbf, xT);
  k1_lin<<<384, 256, 0, stream>>>(inputs, theta_w, phi_w, lin2, spart);
  k3_gemm<<<256, 256, 0, stream>>>(lin2, spart, theta_g, theta_be, phi_g, phi_be,
                                   re_w, p2raw, qTraw, rows8);
  k5_mfma<<<512, 256, 0, stream>>>(wbf, xT, p2raw, qTraw, rows8, re_g, re_be, attp4);
  k67<<<512, 256, 0, stream>>>(attp4, inputs, att_g, att_be, (float*)d_out);
}